// Round 3
// baseline (3365.095 us; speedup 1.0000x reference)
//
#include <hip/hip_runtime.h>
#include <hip/hip_bf16.h>
#include <stdint.h>
#include <math.h>

typedef __bf16 bf16;
typedef __bf16 bf16x8 __attribute__((ext_vector_type(8)));
typedef float f32x4 __attribute__((ext_vector_type(4)));

// B=8, H=W=128, dim=256, mid=128. Inputs/outputs fp32 (per reference dtypes).
// Internal: activations as hi/lo bf16 pairs (2C channels, NHWC, c fastest);
// weights as hi/lo bf16; conv = 3-term (hh + hl + lh) via "virtual taps"
// -> fp32-faithful (~2^-16 rel err per layer).

// ---------------- x: NCHW fp32 -> NHWC hi/lo bf16 (512 ch)
__global__ void k_x_split(const float* __restrict__ in, bf16* __restrict__ out) {
  __shared__ float t[32][33];
  const int b = blockIdx.z;
  const int p0 = blockIdx.x << 5, c0 = blockIdx.y << 5;
  const int tx = threadIdx.x, ty = threadIdx.y;  // block (32,8)
  const float* ib = in + (size_t)b * 256 * 16384;
  bf16* ob = out + (size_t)b * 16384 * 512;
#pragma unroll
  for (int k = 0; k < 32; k += 8)
    t[ty + k][tx] = ib[(size_t)(c0 + ty + k) * 16384 + p0 + tx];
  __syncthreads();
#pragma unroll
  for (int k = 0; k < 32; k += 8) {
    float v = t[tx][ty + k];
    bf16 hv = (bf16)v;
    bf16 lv = (bf16)(v - (float)hv);
    ob[(size_t)(p0 + ty + k) * 512 + c0 + tx] = hv;
    ob[(size_t)(p0 + ty + k) * 512 + 256 + c0 + tx] = lv;
  }
}

// ---------------- weight repack fp32 OIHW -> bf16 [3*tap+v][co][ci]
// v=0: Wh (acts hi), v=1: Wh (acts lo), v=2: Wl (acts hi)
__global__ void k_repack3(const float* __restrict__ src, bf16* __restrict__ dst,
                          int Cout, int Cin, int taps, int coutTotal, int coff) {
  int tid = blockIdx.x * 256 + threadIdx.x;
  int total = Cout * Cin * taps;
  if (tid >= total) return;
  int t = tid % taps;
  int rest = tid / taps;
  int ci = rest % Cin;
  int co = rest / Cin;
  float w = src[tid];
  bf16 wh = (bf16)w;
  bf16 wl = (bf16)(w - (float)wh);
  size_t segsz = (size_t)coutTotal * Cin;
  size_t base = ((size_t)(3 * t) * coutTotal + coff + co) * Cin + ci;
  dst[base] = wh;
  dst[base + segsz] = wh;
  dst[base + 2 * segsz] = wl;
}

// ---------------- BN coefficients (fp32 in, fp32 out)
__global__ void k_bncoef(const float* __restrict__ g, const float* __restrict__ b,
                         const float* __restrict__ m, const float* __restrict__ v,
                         float* __restrict__ sc, float* __restrict__ sh, int n) {
  int c = blockIdx.x * 256 + threadIdx.x;
  if (c >= n) return;
  float s = g[c] * (1.0f / sqrtf(v[c] + 1e-5f));
  sc[c] = s;
  sh[c] = b[c] - m[c] * s;
}

// ---------------- implicit-GEMM conv, bf16 MFMA 16x16x32, fp32 accum
// in: hi/lo act tensor, logical Cin channels, physical row stride rowStride
//     (hi at +0, lo at +Cin within the row).
// Wr: [3*tap+v][co][ci] bf16. Segment v=1 reads act lo (+Cin offset).
// out_mode: 0 = hi/lo bf16 NHWC (2*Cout ch), 1 = fp32 NHWC compact,
//           2 = fp32 NCHW (d_out). addbuf: hi/lo tensor, stride 2*Cout.
__global__ __launch_bounds__(256, 2)
void k_conv(const bf16* __restrict__ in, int Cin, int rowStride,
            const bf16* __restrict__ Wr, int Cout, int ntaps,
            const float* __restrict__ scale, const float* __restrict__ shift,
            const bf16* __restrict__ addbuf, int relu,
            int out_mode, void* __restrict__ out) {
  __shared__ bf16 a_lds[128 * 40];
  __shared__ bf16 b_lds[128 * 40];
  const int row = blockIdx.x;               // b*128 + h
  const int bb = row >> 7, h = row & 127;
  const int co_block = blockIdx.y << 7;
  const int tid = threadIdx.x;
  const int lane = tid & 63, wave = tid >> 6;
  const int wm = (wave >> 1) << 6, wn = (wave & 1) << 6;
  const int quad = lane >> 4, l15 = lane & 15;

  f32x4 acc[4][4];
#pragma unroll
  for (int i = 0; i < 4; ++i)
#pragma unroll
    for (int j = 0; j < 4; ++j)
#pragma unroll
      for (int r = 0; r < 4; ++r) acc[i][j][r] = 0.0f;

  const int srow = tid >> 1;                // staging row: co (A) / pos (B)
  const int kb = (tid & 1) << 4;            // 0/16 within 32-K chunk

  const int nseg = 3 * ntaps;
  for (int seg = 0; seg < nseg; ++seg) {
    const int tap = seg / 3;
    const int v = seg - tap * 3;
    const int dh = (ntaps == 9) ? (tap / 3 - 1) : 0;
    const int dw = (ntaps == 9) ? (tap % 3 - 1) : 0;
    const int aoff = (v == 1) ? Cin : 0;
    const bf16* wseg = Wr + (size_t)seg * Cout * Cin;
    for (int cb = 0; cb < Cin; cb += 32) {
      {
        const bf16* s = wseg + ((size_t)(co_block + srow) * Cin + cb + kb);
        uint4 v0 = *(const uint4*)s;
        uint4 v1 = *(const uint4*)(s + 8);
        *(uint4*)&a_lds[srow * 40 + kb] = v0;
        *(uint4*)&a_lds[srow * 40 + kb + 8] = v1;
      }
      {
        const int hi = h + dh, wi = srow + dw;
        uint4 v0, v1;
        v0.x = v0.y = v0.z = v0.w = 0u;
        v1 = v0;
        if ((unsigned)hi < 128u && (unsigned)wi < 128u) {
          const bf16* s = in + (size_t)((bb * 128 + hi) * 128 + wi) * rowStride + aoff + cb + kb;
          v0 = *(const uint4*)s;
          v1 = *(const uint4*)(s + 8);
        }
        *(uint4*)&b_lds[srow * 40 + kb] = v0;
        *(uint4*)&b_lds[srow * 40 + kb + 8] = v1;
      }
      __syncthreads();
      bf16x8 af[4], bfr[4];
#pragma unroll
      for (int i = 0; i < 4; ++i)
        af[i] = *(const bf16x8*)&a_lds[(wm + i * 16 + l15) * 40 + quad * 8];
#pragma unroll
      for (int j = 0; j < 4; ++j)
        bfr[j] = *(const bf16x8*)&b_lds[(wn + j * 16 + l15) * 40 + quad * 8];
#pragma unroll
      for (int i = 0; i < 4; ++i)
#pragma unroll
        for (int j = 0; j < 4; ++j)
          acc[i][j] = __builtin_amdgcn_mfma_f32_16x16x32_bf16(af[i], bfr[j], acc[i][j], 0, 0, 0);
      __syncthreads();
    }
  }

  // epilogue: D row(m=cout)=quad*4+reg, col(n=pos)=lane&15
#pragma unroll
  for (int i = 0; i < 4; ++i) {
    const int co = co_block + wm + i * 16 + (quad << 2);
#pragma unroll
    for (int j = 0; j < 4; ++j) {
      const int pos = wn + j * 16 + l15;
      float v[4];
#pragma unroll
      for (int r = 0; r < 4; ++r) v[r] = acc[i][j][r];
      if (scale) {
#pragma unroll
        for (int r = 0; r < 4; ++r) v[r] = v[r] * scale[co + r] + shift[co + r];
      }
      if (addbuf) {
        const bf16* ah = addbuf + (size_t)(row * 128 + pos) * (2 * Cout) + co;
        const bf16* al = ah + Cout;
#pragma unroll
        for (int r = 0; r < 4; ++r) v[r] += (float)ah[r] + (float)al[r];
      }
      if (relu) {
#pragma unroll
        for (int r = 0; r < 4; ++r) v[r] = fmaxf(v[r], 0.0f);
      }
      if (out_mode == 0) {
        bf16* ob = (bf16*)out;
        union { bf16 hv[4]; uint2 u; } ph, pl;
#pragma unroll
        for (int r = 0; r < 4; ++r) {
          ph.hv[r] = (bf16)v[r];
          pl.hv[r] = (bf16)(v[r] - (float)ph.hv[r]);
        }
        const size_t base = (size_t)(row * 128 + pos) * (2 * Cout);
        *(uint2*)&ob[base + co] = ph.u;
        *(uint2*)&ob[base + Cout + co] = pl.u;
      } else if (out_mode == 1) {
        float* of = (float*)out;
        float4 pk = make_float4(v[0], v[1], v[2], v[3]);
        *(float4*)&of[(size_t)(row * 128 + pos) * Cout + co] = pk;
      } else {
        float* of = (float*)out;
#pragma unroll
        for (int r = 0; r < 4; ++r)
          of[((size_t)(bb * Cout + co + r) * 128 + h) * 128 + pos] = v[r];
      }
    }
  }
}

// ---------------- pools (fp32 reconstruct, scan, re-split). In-place variants.
// y: 512ch rows [lookH 0:128 | pH 128:256 | lookL 256:384 | pL 384:512]
// writes s = pool(look)+p into ch [0:128) hi, [128:256) lo of the same rows.
__global__ void k_pool_s1(bf16* __restrict__ y) {  // left_pool: scan w
  int tid = blockIdx.x * 256 + threadIdx.x;
  int c = tid & 127, h = (tid >> 7) & 127, b = tid >> 14;
  bf16* base = y + (size_t)((b * 128 + h) * 128) * 512;
  float run = -INFINITY;
  for (int w = 127; w >= 0; --w) {
    bf16* p = base + (size_t)w * 512;
    float look = (float)p[c] + (float)p[256 + c];
    float padd = (float)p[128 + c] + (float)p[384 + c];
    run = fmaxf(run, look);
    float sum = run + padd;
    bf16 hv = (bf16)sum;
    p[c] = hv;
    p[128 + c] = (bf16)(sum - (float)hv);
  }
}
__global__ void k_pool_s2(bf16* __restrict__ y) {  // top_pool: scan h
  int tid = blockIdx.x * 256 + threadIdx.x;
  int c = tid & 127, w = (tid >> 7) & 127, b = tid >> 14;
  bf16* base = y + ((size_t)b * 16384 + w) * 512;
  float run = -INFINITY;
  for (int hh = 127; hh >= 0; --hh) {
    bf16* p = base + (size_t)hh * 65536;
    float look = (float)p[c] + (float)p[256 + c];
    float padd = (float)p[128 + c] + (float)p[384 + c];
    run = fmaxf(run, look);
    float sum = run + padd;
    bf16 hv = (bf16)sum;
    p[c] = hv;
    p[128 + c] = (bf16)(sum - (float)hv);
  }
}
// in-place top_pool over fp32 (C=128)
__global__ void k_tpool_f(float* __restrict__ buf) {
  int tid = blockIdx.x * 256 + threadIdx.x;
  int c = tid & 127, w = (tid >> 7) & 127, b = tid >> 14;
  float* p = buf + ((size_t)b * 16384 + w) * 128 + c;
  float run = -INFINITY;
  for (int hh = 127; hh >= 0; --hh) {
    run = fmaxf(run, p[(size_t)hh * 16384]);
    p[(size_t)hh * 16384] = run;
  }
}
// psum = left_pool(p2lk fp32) + ptmp fp32 -> hi/lo compact (256 ch)
__global__ void k_lpool_add_f(const float* __restrict__ in, const float* __restrict__ addb,
                              bf16* __restrict__ out) {
  int tid = blockIdx.x * 256 + threadIdx.x;
  int c = tid & 127, h = (tid >> 7) & 127, b = tid >> 14;
  const float* p = in + (size_t)((b * 128 + h) * 128) * 128 + c;
  const float* a = addb + (size_t)((b * 128 + h) * 128) * 128 + c;
  bf16* o = out + (size_t)((b * 128 + h) * 128) * 256;
  float run = -INFINITY;
  for (int w = 127; w >= 0; --w) {
    run = fmaxf(run, p[(size_t)w * 128]);
    float sum = run + a[(size_t)w * 128];
    bf16 hv = (bf16)sum;
    o[(size_t)w * 256 + c] = hv;
    o[(size_t)w * 256 + 128 + c] = (bf16)(sum - (float)hv);
  }
}

extern "C" void kernel_launch(void* const* d_in, const int* in_sizes, int n_in,
                              void* d_out, int out_size, void* d_ws, size_t ws_size,
                              hipStream_t stream) {
  (void)in_sizes; (void)n_in; (void)out_size; (void)ws_size;
#define INF(i) ((const float*)d_in[i])
  char* ws = (char*)d_ws;
  const size_t MB = 1 << 20;
  // weights [0, 15MB)
  bf16* wrA  = (bf16*)(ws + 0);           // 27*256*256 (lc1|p1c1)
  bf16* wrB  = (bf16*)(ws + 3538944);     // 27*256*256 (lc2|p2c1)
  bf16* wrp1 = (bf16*)(ws + 7077888);     // 27*128*128
  bf16* wrp2 = (bf16*)(ws + 7962624);
  bf16* wrpc = (bf16*)(ws + 8847360);     // 27*256*128
  bf16* wrc1 = (bf16*)(ws + 10616832);    // 3*256*256
  bf16* wrc2 = (bf16*)(ws + 11010048);    // 27*256*256
  float* scA  = (float*)(ws + 14680064);
  float* shA  = (float*)(ws + 14684160);
  float* scB  = (float*)(ws + 14688256);
  float* shB  = (float*)(ws + 14692352);
  float* scp  = (float*)(ws + 14696448);
  float* shp  = (float*)(ws + 14700544);
  float* scb  = (float*)(ws + 14704640);
  float* shb  = (float*)(ws + 14708736);
  float* scc2 = (float*)(ws + 14712832);
  float* shc2 = (float*)(ws + 14716928);
  // activation regions (total ws use: 335 MB; d_out doubles as 128MB scratch)
  bf16*  x_hl  = (bf16*)(ws + 15 * MB);    // 128 MB hi/lo x, live thru mergedB
  bf16*  bnrel = (bf16*)(ws + 143 * MB);   // 128 MB: bn1 -> (in-place) relu1
  float* p1lk  = (float*)(ws + 271 * MB);  // 64 MB fp32 (later ptmp in-place)
  float* p2lk  = (float*)(ws + 15 * MB);   // 64 MB fp32 (over dead x_hl)
  bf16*  psum  = (bf16*)(ws + 79 * MB);    // 64 MB hi/lo compact 256ch
  bf16*  yscr  = (bf16*)d_out;             // 128 MB: yA / s1, then yB / s2

  // 1) x -> NHWC hi/lo
  k_x_split<<<dim3(512, 8, 8), dim3(32, 8), 0, stream>>>(INF(0), x_hl);

  // 2) weight repacks (3-term virtual taps)
  k_repack3<<<1152, 256, 0, stream>>>(INF(1),  wrA,  128, 256, 9, 256, 0);
  k_repack3<<<1152, 256, 0, stream>>>(INF(6),  wrA,  128, 256, 9, 256, 128);
  k_repack3<<<1152, 256, 0, stream>>>(INF(11), wrB,  128, 256, 9, 256, 0);
  k_repack3<<<1152, 256, 0, stream>>>(INF(16), wrB,  128, 256, 9, 256, 128);
  k_repack3<<<576,  256, 0, stream>>>(INF(21), wrp1, 128, 128, 9, 128, 0);
  k_repack3<<<576,  256, 0, stream>>>(INF(22), wrp2, 128, 128, 9, 128, 0);
  k_repack3<<<1152, 256, 0, stream>>>(INF(23), wrpc, 256, 128, 9, 256, 0);
  k_repack3<<<256,  256, 0, stream>>>(INF(28), wrc1, 256, 256, 1, 256, 0);
  k_repack3<<<2304, 256, 0, stream>>>(INF(33), wrc2, 256, 256, 9, 256, 0);

  // 3) BN coefficients
  k_bncoef<<<1, 256, 0, stream>>>(INF(2),  INF(3),  INF(4),  INF(5),  scA,       shA,       128);
  k_bncoef<<<1, 256, 0, stream>>>(INF(7),  INF(8),  INF(9),  INF(10), scA + 128, shA + 128, 128);
  k_bncoef<<<1, 256, 0, stream>>>(INF(12), INF(13), INF(14), INF(15), scB,       shB,       128);
  k_bncoef<<<1, 256, 0, stream>>>(INF(17), INF(18), INF(19), INF(20), scB + 128, shB + 128, 128);
  k_bncoef<<<1, 256, 0, stream>>>(INF(24), INF(25), INF(26), INF(27), scp, shp, 256);
  k_bncoef<<<1, 256, 0, stream>>>(INF(29), INF(30), INF(31), INF(32), scb, shb, 256);
  k_bncoef<<<1, 256, 0, stream>>>(INF(34), INF(35), INF(36), INF(37), scc2, shc2, 256);

  // 4) bn1 = BN(conv1x1(x)) -> bnrel (hi/lo)
  k_conv<<<dim3(1024, 2), 256, 0, stream>>>(x_hl, 256, 512, wrc1, 256, 1, scb, shb, nullptr, 0, 0, bnrel);
  // 5) yA = [look_conv1 | p1_conv1] (BN+ReLU) -> d_out scratch
  k_conv<<<dim3(1024, 2), 256, 0, stream>>>(x_hl, 256, 512, wrA, 256, 9, scA, shA, nullptr, 1, 0, yscr);
  // 6) s1 = left_pool(look1) + p1_conv1 (in-place in yA, ch [0:256))
  k_pool_s1<<<512, 256, 0, stream>>>(yscr);
  // 7) p1_look = conv(s1, p1lc) -> fp32
  k_conv<<<dim3(1024, 1), 256, 0, stream>>>(yscr, 128, 512, wrp1, 128, 9, nullptr, nullptr, nullptr, 0, 1, p1lk);
  // 8) yB = [look_conv2 | p2_conv1] -> d_out scratch (x dead after this)
  k_conv<<<dim3(1024, 2), 256, 0, stream>>>(x_hl, 256, 512, wrB, 256, 9, scB, shB, nullptr, 1, 0, yscr);
  // 9) s2 = top_pool(look2) + p2_conv1 (in-place)
  k_pool_s2<<<512, 256, 0, stream>>>(yscr);
  // 10) p2_look = conv(s2, p2lc) -> fp32 (over dead x_hl)
  k_conv<<<dim3(1024, 1), 256, 0, stream>>>(yscr, 128, 512, wrp2, 128, 9, nullptr, nullptr, nullptr, 0, 1, p2lk);
  // 11) ptmp = top_pool(p1_look) in-place
  k_tpool_f<<<512, 256, 0, stream>>>(p1lk);
  // 12) psum = left_pool(p2_look) + ptmp -> hi/lo compact
  k_lpool_add_f<<<512, 256, 0, stream>>>(p2lk, p1lk, psum);
  // 13) relu1 = relu(BN(conv(psum, pconv1)) + bn1) -> in-place over bn1
  k_conv<<<dim3(1024, 2), 256, 0, stream>>>(psum, 128, 256, wrpc, 256, 9, scp, shp, bnrel, 1, 0, bnrel);
  // 14) out = relu(BN(conv(relu1, c2))) -> NCHW fp32 d_out
  k_conv<<<dim3(1024, 2), 256, 0, stream>>>(bnrel, 256, 512, wrc2, 256, 9, scc2, shc2, nullptr, 1, 2, (float*)d_out);
#undef INF
}

// Round 4
// 2824.811 us; speedup vs baseline: 1.1913x; 1.1913x over previous
//
#include <hip/hip_runtime.h>
#include <hip/hip_bf16.h>
#include <stdint.h>
#include <math.h>

typedef __bf16 bf16;
typedef __bf16 bf16x8 __attribute__((ext_vector_type(8)));
typedef float f32x4 __attribute__((ext_vector_type(4)));

// B=8, H=W=128, dim=256, mid=128. fp32 I/O; internal hi/lo bf16 pairs.
// conv = 3-term bf16 (WhAh + WhAl + WlAh) via per-tap Wh||Wl staging against a
// once-per-chunk 3x130 input slab in LDS (tap reuse: 27x fewer global B reads).

// ---------------- x: NCHW fp32 -> NHWC hi/lo bf16 (512 ch)
__global__ void k_x_split(const float* __restrict__ in, bf16* __restrict__ out) {
  __shared__ float t[32][33];
  const int b = blockIdx.z;
  const int p0 = blockIdx.x << 5, c0 = blockIdx.y << 5;
  const int tx = threadIdx.x, ty = threadIdx.y;  // block (32,8)
  const float* ib = in + (size_t)b * 256 * 16384;
  bf16* ob = out + (size_t)b * 16384 * 512;
#pragma unroll
  for (int k = 0; k < 32; k += 8)
    t[ty + k][tx] = ib[(size_t)(c0 + ty + k) * 16384 + p0 + tx];
  __syncthreads();
#pragma unroll
  for (int k = 0; k < 32; k += 8) {
    float v = t[tx][ty + k];
    bf16 hv = (bf16)v;
    bf16 lv = (bf16)(v - (float)hv);
    ob[(size_t)(p0 + ty + k) * 512 + c0 + tx] = hv;
    ob[(size_t)(p0 + ty + k) * 512 + 256 + c0 + tx] = lv;
  }
}

// ---------------- weight repack fp32 OIHW -> bf16 [2*tap+s][co][ci] (s=0 Wh, s=1 Wl)
__global__ void k_repack2(const float* __restrict__ src, bf16* __restrict__ dst,
                          int Cout, int Cin, int taps, int coutTotal, int coff) {
  int tid = blockIdx.x * 256 + threadIdx.x;
  int total = Cout * Cin * taps;
  if (tid >= total) return;
  int t = tid % taps;
  int rest = tid / taps;
  int ci = rest % Cin;
  int co = rest / Cin;
  float w = src[tid];
  bf16 wh = (bf16)w;
  bf16 wl = (bf16)(w - (float)wh);
  size_t segsz = (size_t)coutTotal * Cin;
  size_t base = ((size_t)(2 * t) * coutTotal + coff + co) * Cin + ci;
  dst[base] = wh;
  dst[base + segsz] = wl;
}

// ---------------- BN coefficients
__global__ void k_bncoef(const float* __restrict__ g, const float* __restrict__ b,
                         const float* __restrict__ m, const float* __restrict__ v,
                         float* __restrict__ sc, float* __restrict__ sh, int n) {
  int c = blockIdx.x * 256 + threadIdx.x;
  if (c >= n) return;
  float s = g[c] * (1.0f / sqrtf(v[c] + 1e-5f));
  sc[c] = s;
  sh[c] = b[c] - m[c] * s;
}

// ---------------- implicit-GEMM conv with tap-reuse slab staging
// in: hi/lo act tensor (hi at +0, lo at +Cin within rowStride-ch rows).
// Wr: [2*tap+s][co][ci]. out_mode: 0 = hi/lo bf16 NHWC (2*Cout ch),
// 1 = fp32 NHWC compact, 2 = fp32 NCHW. addbuf: hi/lo, stride 2*Cout.
__global__ __launch_bounds__(256, 2)
void k_conv(const bf16* __restrict__ in, int Cin, int rowStride,
            const bf16* __restrict__ Wr, int Cout, int ntaps,
            const float* __restrict__ scale, const float* __restrict__ shift,
            const bf16* __restrict__ addbuf, int relu,
            int out_mode, void* __restrict__ out) {
  __shared__ bf16 a_lds[2 * 128 * 32];   // Wh rows [0:128), Wl rows [128:256)
  __shared__ bf16 b_slab[6 * 130 * 32];  // plane = hl*R + r; pos -1..128 at +1
  const int R = (ntaps == 9) ? 3 : 1;
  const int bx = blockIdx.x;
  const int bb = bx & 7, h = (bx >> 3) & 127;   // XCD swizzle: batch == XCD
  const int row = bb * 128 + h;
  const int co_block = blockIdx.y << 7;
  const int tid = threadIdx.x;
  const int lane = tid & 63, wave = tid >> 6;
  const int wm = (wave >> 1) << 6, wn = (wave & 1) << 6;
  const int quad = lane >> 4, l15 = lane & 15;

  f32x4 acc[4][4];
#pragma unroll
  for (int i = 0; i < 4; ++i)
#pragma unroll
    for (int j = 0; j < 4; ++j)
#pragma unroll
      for (int r = 0; r < 4; ++r) acc[i][j][r] = 0.0f;

  const int nunits = 2 * R * 130;
  const int as = tid >> 7, aco = tid & 127;  // A staging role

  for (int cb = 0; cb < Cin; cb += 32) {
    // ---- stage B slab (once per chunk): 2(hl) x R rows x 130 pos x 32 ch
    for (int u = tid; u < nunits; u += 256) {
      int plane = u / 130, p = u - plane * 130;
      int hl, r;
      if (R == 3) { hl = plane >= 3; r = plane - (hl ? 3 : 0); }
      else        { hl = plane; r = 0; }
      int hi = h + r - (R == 3 ? 1 : 0);
      int wi = p - 1;
      uint4 v0, v1, v2, v3;
      v0.x = v0.y = v0.z = v0.w = 0u; v1 = v0; v2 = v0; v3 = v0;
      if ((unsigned)hi < 128u && (unsigned)wi < 128u) {
        const bf16* s = in + (size_t)((bb * 128 + hi) * 128 + wi) * rowStride
                        + (size_t)hl * Cin + cb;
        v0 = *(const uint4*)s;
        v1 = *(const uint4*)(s + 8);
        v2 = *(const uint4*)(s + 16);
        v3 = *(const uint4*)(s + 24);
      }
      bf16* d = &b_slab[(size_t)(plane * 130 + p) * 32];
      *(uint4*)d = v0;
      *(uint4*)(d + 8) = v1;
      *(uint4*)(d + 16) = v2;
      *(uint4*)(d + 24) = v3;
    }
    for (int tap = 0; tap < ntaps; ++tap) {
      // ---- stage A: Wh (seg 2*tap) and Wl (seg 2*tap+1), 64 B/thread
      {
        const bf16* s = Wr + ((size_t)(2 * tap + as) * Cout + co_block + aco) * Cin + cb;
        uint4 w0 = *(const uint4*)s;
        uint4 w1 = *(const uint4*)(s + 8);
        uint4 w2 = *(const uint4*)(s + 16);
        uint4 w3 = *(const uint4*)(s + 24);
        bf16* d = &a_lds[(size_t)(as * 128 + aco) * 32];
        *(uint4*)d = w0;
        *(uint4*)(d + 8) = w1;
        *(uint4*)(d + 16) = w2;
        *(uint4*)(d + 24) = w3;
      }
      __syncthreads();
      const int rr = (R == 3) ? (tap / 3) : 0;        // slab row
      const int wc = (R == 3) ? (tap % 3) : 1;        // dw+1 column offset
      const int bH = (0 * R + rr) * 130;
      const int bL = (1 * R + rr) * 130;
      bf16x8 afH[4], afL[4], bfH[4], bfL[4];
#pragma unroll
      for (int i = 0; i < 4; ++i) {
        afH[i] = *(const bf16x8*)&a_lds[(size_t)(wm + i * 16 + l15) * 32 + quad * 8];
        afL[i] = *(const bf16x8*)&a_lds[(size_t)(128 + wm + i * 16 + l15) * 32 + quad * 8];
      }
#pragma unroll
      for (int j = 0; j < 4; ++j) {
        const int p_idx = wn + j * 16 + l15 + wc;
        bfH[j] = *(const bf16x8*)&b_slab[(size_t)(bH + p_idx) * 32 + quad * 8];
        bfL[j] = *(const bf16x8*)&b_slab[(size_t)(bL + p_idx) * 32 + quad * 8];
      }
#pragma unroll
      for (int i = 0; i < 4; ++i)
#pragma unroll
        for (int j = 0; j < 4; ++j) {
          acc[i][j] = __builtin_amdgcn_mfma_f32_16x16x32_bf16(afH[i], bfH[j], acc[i][j], 0, 0, 0);
          acc[i][j] = __builtin_amdgcn_mfma_f32_16x16x32_bf16(afH[i], bfL[j], acc[i][j], 0, 0, 0);
          acc[i][j] = __builtin_amdgcn_mfma_f32_16x16x32_bf16(afL[i], bfH[j], acc[i][j], 0, 0, 0);
        }
      __syncthreads();
    }
  }

  // epilogue: D row(m=cout)=quad*4+reg, col(n=pos)=lane&15
#pragma unroll
  for (int i = 0; i < 4; ++i) {
    const int co = co_block + wm + i * 16 + (quad << 2);
#pragma unroll
    for (int j = 0; j < 4; ++j) {
      const int pos = wn + j * 16 + l15;
      float v[4];
#pragma unroll
      for (int r = 0; r < 4; ++r) v[r] = acc[i][j][r];
      if (scale) {
#pragma unroll
        for (int r = 0; r < 4; ++r) v[r] = v[r] * scale[co + r] + shift[co + r];
      }
      if (addbuf) {
        const bf16* ah = addbuf + (size_t)(row * 128 + pos) * (2 * Cout) + co;
        const bf16* al = ah + Cout;
#pragma unroll
        for (int r = 0; r < 4; ++r) v[r] += (float)ah[r] + (float)al[r];
      }
      if (relu) {
#pragma unroll
        for (int r = 0; r < 4; ++r) v[r] = fmaxf(v[r], 0.0f);
      }
      if (out_mode == 0) {
        bf16* ob = (bf16*)out;
        union { bf16 hv[4]; uint2 u; } ph, pl;
#pragma unroll
        for (int r = 0; r < 4; ++r) {
          ph.hv[r] = (bf16)v[r];
          pl.hv[r] = (bf16)(v[r] - (float)ph.hv[r]);
        }
        const size_t base = (size_t)(row * 128 + pos) * (2 * Cout);
        *(uint2*)&ob[base + co] = ph.u;
        *(uint2*)&ob[base + Cout + co] = pl.u;
      } else if (out_mode == 1) {
        float* of = (float*)out;
        float4 pk = make_float4(v[0], v[1], v[2], v[3]);
        *(float4*)&of[(size_t)(row * 128 + pos) * Cout + co] = pk;
      } else {
        float* of = (float*)out;
#pragma unroll
        for (int r = 0; r < 4; ++r)
          of[((size_t)(bb * Cout + co + r) * 128 + h) * 128 + pos] = v[r];
      }
    }
  }
}

// ---------------- pools (fp32 reconstruct, scan, re-split), in-place
// y: 512ch rows [lookH 0:128 | pH 128:256 | lookL 256:384 | pL 384:512]
__global__ void k_pool_s1(bf16* __restrict__ y) {  // left_pool: scan w
  int tid = blockIdx.x * 256 + threadIdx.x;
  int c = tid & 127, h = (tid >> 7) & 127, b = tid >> 14;
  bf16* base = y + (size_t)((b * 128 + h) * 128) * 512;
  float run = -INFINITY;
  for (int w = 127; w >= 0; --w) {
    bf16* p = base + (size_t)w * 512;
    float look = (float)p[c] + (float)p[256 + c];
    float padd = (float)p[128 + c] + (float)p[384 + c];
    run = fmaxf(run, look);
    float sum = run + padd;
    bf16 hv = (bf16)sum;
    p[c] = hv;
    p[128 + c] = (bf16)(sum - (float)hv);
  }
}
__global__ void k_pool_s2(bf16* __restrict__ y) {  // top_pool: scan h
  int tid = blockIdx.x * 256 + threadIdx.x;
  int c = tid & 127, w = (tid >> 7) & 127, b = tid >> 14;
  bf16* base = y + ((size_t)b * 16384 + w) * 512;
  float run = -INFINITY;
  for (int hh = 127; hh >= 0; --hh) {
    bf16* p = base + (size_t)hh * 65536;
    float look = (float)p[c] + (float)p[256 + c];
    float padd = (float)p[128 + c] + (float)p[384 + c];
    run = fmaxf(run, look);
    float sum = run + padd;
    bf16 hv = (bf16)sum;
    p[c] = hv;
    p[128 + c] = (bf16)(sum - (float)hv);
  }
}
__global__ void k_tpool_f(float* __restrict__ buf) {  // in-place top_pool fp32
  int tid = blockIdx.x * 256 + threadIdx.x;
  int c = tid & 127, w = (tid >> 7) & 127, b = tid >> 14;
  float* p = buf + ((size_t)b * 16384 + w) * 128 + c;
  float run = -INFINITY;
  for (int hh = 127; hh >= 0; --hh) {
    run = fmaxf(run, p[(size_t)hh * 16384]);
    p[(size_t)hh * 16384] = run;
  }
}
__global__ void k_lpool_add_f(const float* __restrict__ in, const float* __restrict__ addb,
                              bf16* __restrict__ out) {
  int tid = blockIdx.x * 256 + threadIdx.x;
  int c = tid & 127, h = (tid >> 7) & 127, b = tid >> 14;
  const float* p = in + (size_t)((b * 128 + h) * 128) * 128 + c;
  const float* a = addb + (size_t)((b * 128 + h) * 128) * 128 + c;
  bf16* o = out + (size_t)((b * 128 + h) * 128) * 256;
  float run = -INFINITY;
  for (int w = 127; w >= 0; --w) {
    run = fmaxf(run, p[(size_t)w * 128]);
    float sum = run + a[(size_t)w * 128];
    bf16 hv = (bf16)sum;
    o[(size_t)w * 256 + c] = hv;
    o[(size_t)w * 256 + 128 + c] = (bf16)(sum - (float)hv);
  }
}

extern "C" void kernel_launch(void* const* d_in, const int* in_sizes, int n_in,
                              void* d_out, int out_size, void* d_ws, size_t ws_size,
                              hipStream_t stream) {
  (void)in_sizes; (void)n_in; (void)out_size; (void)ws_size;
#define INF(i) ((const float*)d_in[i])
  char* ws = (char*)d_ws;
  const size_t MB = 1 << 20;
  // weights [0, ~9.75MB): [2*tap+s][co][ci]
  bf16* wrA  = (bf16*)(ws + 0);          // 18*256*256
  bf16* wrB  = (bf16*)(ws + 2359296);
  bf16* wrp1 = (bf16*)(ws + 4718592);    // 18*128*128
  bf16* wrp2 = (bf16*)(ws + 5308416);
  bf16* wrpc = (bf16*)(ws + 5898240);    // 18*256*128
  bf16* wrc1 = (bf16*)(ws + 7077888);    // 2*256*256
  bf16* wrc2 = (bf16*)(ws + 7340032);    // 18*256*256
  float* scA  = (float*)(ws + 9699328);
  float* shA  = (float*)(ws + 9703424);
  float* scB  = (float*)(ws + 9707520);
  float* shB  = (float*)(ws + 9711616);
  float* scp  = (float*)(ws + 9715712);
  float* shp  = (float*)(ws + 9719808);
  float* scb  = (float*)(ws + 9723904);
  float* shb  = (float*)(ws + 9728000);
  float* scc2 = (float*)(ws + 9732096);
  float* shc2 = (float*)(ws + 9736192);
  // activations (ws use <= 330 MB; d_out doubles as 128 MB scratch)
  bf16*  x_hl  = (bf16*)(ws + 10 * MB);    // 128 MB, live thru step 8
  bf16*  bnrel = (bf16*)(ws + 138 * MB);   // 128 MB: bn1 -> relu1 in-place
  float* p1lk  = (float*)(ws + 266 * MB);  // 64 MB fp32
  float* p2lk  = (float*)(ws + 10 * MB);   // 64 MB fp32 over dead x_hl
  bf16*  psum  = (bf16*)(ws + 74 * MB);    // 64 MB hi/lo compact 256ch
  bf16*  yscr  = (bf16*)d_out;             // 128 MB scratch: yA/s1 then yB/s2

  // 1) x -> NHWC hi/lo
  k_x_split<<<dim3(512, 8, 8), dim3(32, 8), 0, stream>>>(INF(0), x_hl);

  // 2) weight repacks (Wh/Wl segments)
  k_repack2<<<1152, 256, 0, stream>>>(INF(1),  wrA,  128, 256, 9, 256, 0);
  k_repack2<<<1152, 256, 0, stream>>>(INF(6),  wrA,  128, 256, 9, 256, 128);
  k_repack2<<<1152, 256, 0, stream>>>(INF(11), wrB,  128, 256, 9, 256, 0);
  k_repack2<<<1152, 256, 0, stream>>>(INF(16), wrB,  128, 256, 9, 256, 128);
  k_repack2<<<576,  256, 0, stream>>>(INF(21), wrp1, 128, 128, 9, 128, 0);
  k_repack2<<<576,  256, 0, stream>>>(INF(22), wrp2, 128, 128, 9, 128, 0);
  k_repack2<<<1152, 256, 0, stream>>>(INF(23), wrpc, 256, 128, 9, 256, 0);
  k_repack2<<<256,  256, 0, stream>>>(INF(28), wrc1, 256, 256, 1, 256, 0);
  k_repack2<<<2304, 256, 0, stream>>>(INF(33), wrc2, 256, 256, 9, 256, 0);

  // 3) BN coefficients
  k_bncoef<<<1, 256, 0, stream>>>(INF(2),  INF(3),  INF(4),  INF(5),  scA,       shA,       128);
  k_bncoef<<<1, 256, 0, stream>>>(INF(7),  INF(8),  INF(9),  INF(10), scA + 128, shA + 128, 128);
  k_bncoef<<<1, 256, 0, stream>>>(INF(12), INF(13), INF(14), INF(15), scB,       shB,       128);
  k_bncoef<<<1, 256, 0, stream>>>(INF(17), INF(18), INF(19), INF(20), scB + 128, shB + 128, 128);
  k_bncoef<<<1, 256, 0, stream>>>(INF(24), INF(25), INF(26), INF(27), scp, shp, 256);
  k_bncoef<<<1, 256, 0, stream>>>(INF(29), INF(30), INF(31), INF(32), scb, shb, 256);
  k_bncoef<<<1, 256, 0, stream>>>(INF(34), INF(35), INF(36), INF(37), scc2, shc2, 256);

  // 4) bn1 = BN(conv1x1(x)) -> bnrel (hi/lo)
  k_conv<<<dim3(1024, 2), 256, 0, stream>>>(x_hl, 256, 512, wrc1, 256, 1, scb, shb, nullptr, 0, 0, bnrel);
  // 5) yA = [look_conv1 | p1_conv1] (BN+ReLU) -> d_out scratch
  k_conv<<<dim3(1024, 2), 256, 0, stream>>>(x_hl, 256, 512, wrA, 256, 9, scA, shA, nullptr, 1, 0, yscr);
  // 6) s1 = left_pool(look1) + p1_conv1 (in-place, ch [0:256))
  k_pool_s1<<<512, 256, 0, stream>>>(yscr);
  // 7) p1_look = conv(s1, p1lc) -> fp32
  k_conv<<<dim3(1024, 1), 256, 0, stream>>>(yscr, 128, 512, wrp1, 128, 9, nullptr, nullptr, nullptr, 0, 1, p1lk);
  // 8) yB = [look_conv2 | p2_conv1] -> d_out scratch (x dead after)
  k_conv<<<dim3(1024, 2), 256, 0, stream>>>(x_hl, 256, 512, wrB, 256, 9, scB, shB, nullptr, 1, 0, yscr);
  // 9) s2 = top_pool(look2) + p2_conv1 (in-place)
  k_pool_s2<<<512, 256, 0, stream>>>(yscr);
  // 10) p2_look = conv(s2, p2lc) -> fp32 (over dead x_hl)
  k_conv<<<dim3(1024, 1), 256, 0, stream>>>(yscr, 128, 512, wrp2, 128, 9, nullptr, nullptr, nullptr, 0, 1, p2lk);
  // 11) ptmp = top_pool(p1_look) in-place
  k_tpool_f<<<512, 256, 0, stream>>>(p1lk);
  // 12) psum = left_pool(p2_look) + ptmp -> hi/lo compact
  k_lpool_add_f<<<512, 256, 0, stream>>>(p2lk, p1lk, psum);
  // 13) relu1 = relu(BN(conv(psum, pconv1)) + bn1) in-place over bn1
  k_conv<<<dim3(1024, 2), 256, 0, stream>>>(psum, 128, 256, wrpc, 256, 9, scp, shp, bnrel, 1, 0, bnrel);
  // 14) out = relu(BN(conv(relu1, c2))) -> NCHW fp32 d_out
  k_conv<<<dim3(1024, 2), 256, 0, stream>>>(bnrel, 256, 512, wrc2, 256, 9, scc2, shc2, nullptr, 1, 2, (float*)d_out);
#undef INF
}